// Round 1
// baseline (2741.561 us; speedup 1.0000x reference)
//
#include <hip/hip_runtime.h>

#define CNUM 29
#define HH 256
#define WW 256
#define BB 2
#define KK 7
#define HALO 3
#define TX 32
#define TY 8
#define LW (TX + 2*HALO)   // 38
#define LH (TY + 2*HALO)   // 14
#define HWP (HH*WW)        // 65536

__device__ __forceinline__ void compute_spatial(float* sw) {
    float g[KK];
    float s = 0.f;
#pragma unroll
    for (int i = 0; i < KK; ++i) {
        float d = (float)i - 3.0f;
        g[i] = __expf(-d * d / 18.0f);   // 2*sigma^2 = 18
        s += g[i];
    }
    float inv = 1.0f / s;
#pragma unroll
    for (int i = 0; i < KK; ++i) g[i] *= inv;
#pragma unroll
    for (int i = 0; i < KK; ++i)
#pragma unroll
        for (int j = 0; j < KK; ++j) sw[i * KK + j] = g[i] * g[j];
}

__global__ __launch_bounds__(256) void init_q(const float* __restrict__ unary,
                                              float* __restrict__ q) {
    int idx = blockIdx.x * 256 + threadIdx.x;
    if (idx >= BB * HWP) return;
    int b = idx >> 16;          // idx / HWP
    int pix = idx & (HWP - 1);  // idx % HWP
    const float* ub = unary + (size_t)b * CNUM * HWP + pix;
    float l[CNUM];
    float m = -1e30f;
#pragma unroll
    for (int c = 0; c < CNUM; ++c) {
        l[c] = -ub[(size_t)c * HWP];
        m = fmaxf(m, l[c]);
    }
    float s = 0.f;
#pragma unroll
    for (int c = 0; c < CNUM; ++c) {
        l[c] = __expf(l[c] - m);
        s += l[c];
    }
    float inv = 1.0f / s;
    float* qo = q + (size_t)b * CNUM * HWP + pix;
#pragma unroll
    for (int c = 0; c < CNUM; ++c) qo[(size_t)c * HWP] = l[c] * inv;
}

__global__ __launch_bounds__(256) void crf_step(const float* __restrict__ unary,
                                                const float* __restrict__ img,
                                                const float* __restrict__ qin,
                                                float* __restrict__ qout) {
    __shared__ float s_img[3][LH][LW];
    __shared__ float s_q[LH][LW];

    const int tid = threadIdx.x;
    const int tx = tid & (TX - 1);
    const int ty = tid >> 5;
    const int bx = blockIdx.x * TX;
    const int by = blockIdx.y * TY;
    const int b  = blockIdx.z;
    const int x = bx + tx;
    const int y = by + ty;

    // ---- Phase 1: stage img halo tile (3 channels), build 49 combined weights ----
    const float* imgb = img + (size_t)b * 3 * HWP;
    for (int t = tid; t < LH * LW; t += 256) {
        int r  = t / LW;
        int cc = t - r * LW;
        int gy = by + r - HALO;
        int gx = bx + cc - HALO;
        bool ok = (gy >= 0) && (gy < HH) && (gx >= 0) && (gx < WW);
        int goff = gy * WW + gx;
#pragma unroll
        for (int ch = 0; ch < 3; ++ch)
            s_img[ch][r][cc] = ok ? imgb[(size_t)ch * HWP + goff] : 0.f;
    }
    __syncthreads();

    float sw[KK * KK];
    compute_spatial(sw);

    const float c0 = s_img[0][ty + HALO][tx + HALO];
    const float c1 = s_img[1][ty + HALO][tx + HALO];
    const float c2 = s_img[2][ty + HALO][tx + HALO];

    float wgt[KK * KK];
#pragma unroll
    for (int i = 0; i < KK; ++i) {
#pragma unroll
        for (int j = 0; j < KK; ++j) {
            float d0 = s_img[0][ty + i][tx + j] - c0;
            float d1 = s_img[1][ty + i][tx + j] - c1;
            float d2 = s_img[2][ty + i][tx + j] - c2;
            float ds = d0 * d0 + d1 * d1 + d2 * d2;
            // combined: sw * (COMPAT_G + COMPAT_B * exp(-ds / (2*SRGB^2)))
            wgt[i * KK + j] = sw[i * KK + j] * (3.0f + 10.0f * __expf(-ds * 0.005f));
        }
    }

    // ---- Phase 2: per-channel message passing ----
    const float* qb = qin + (size_t)b * CNUM * HWP;
    const float* ub = unary + (size_t)b * CNUM * HWP;
    float l[CNUM];
#pragma unroll
    for (int c = 0; c < CNUM; ++c) {
        __syncthreads();  // protect s_q reuse
        for (int t = tid; t < LH * LW; t += 256) {
            int r  = t / LW;
            int cc = t - r * LW;
            int gy = by + r - HALO;
            int gx = bx + cc - HALO;
            bool ok = (gy >= 0) && (gy < HH) && (gx >= 0) && (gx < WW);
            s_q[r][cc] = ok ? qb[(size_t)c * HWP + gy * WW + gx] : 0.f;
        }
        __syncthreads();
        float acc = 0.f;
#pragma unroll
        for (int i = 0; i < KK; ++i)
#pragma unroll
            for (int j = 0; j < KK; ++j)
                acc += wgt[i * KK + j] * s_q[ty + i][tx + j];
        l[c] = acc - ub[(size_t)c * HWP + y * WW + x];
    }

    // ---- softmax over channels ----
    float m = l[0];
#pragma unroll
    for (int c = 1; c < CNUM; ++c) m = fmaxf(m, l[c]);
    float s = 0.f;
#pragma unroll
    for (int c = 0; c < CNUM; ++c) {
        l[c] = __expf(l[c] - m);
        s += l[c];
    }
    float inv = 1.0f / s;
    float* qo = qout + (size_t)b * CNUM * HWP;
#pragma unroll
    for (int c = 0; c < CNUM; ++c) qo[(size_t)c * HWP + y * WW + x] = l[c] * inv;
}

extern "C" void kernel_launch(void* const* d_in, const int* in_sizes, int n_in,
                              void* d_out, int out_size, void* d_ws, size_t ws_size,
                              hipStream_t stream) {
    const float* unary = (const float*)d_in[0];
    const float* img   = (const float*)d_in[1];
    float* qA = (float*)d_ws;    // needs BB*CNUM*HWP*4 = 15,204,352 bytes
    float* qB = (float*)d_out;

    init_q<<<dim3((BB * HWP + 255) / 256), 256, 0, stream>>>(unary, qA);

    dim3 grid(WW / TX, HH / TY, BB);
    crf_step<<<grid, 256, 0, stream>>>(unary, img, qA, qB);  // iter 1
    crf_step<<<grid, 256, 0, stream>>>(unary, img, qB, qA);  // iter 2
    crf_step<<<grid, 256, 0, stream>>>(unary, img, qA, qB);  // iter 3
    crf_step<<<grid, 256, 0, stream>>>(unary, img, qB, qA);  // iter 4
    crf_step<<<grid, 256, 0, stream>>>(unary, img, qA, qB);  // iter 5 -> d_out
}

// Round 2
// 277.824 us; speedup vs baseline: 9.8680x; 9.8680x over previous
//
#include <hip/hip_runtime.h>

#define CNUM 29
#define CG 8          // channels per block
#define NGRP 4        // ceil(29/8)
#define HH 256
#define WW 256
#define BB 2
#define KK 7
#define HALO 3
#define TX 32
#define TY 8
#define LW (TX + 2*HALO)   // 38
#define LH (TY + 2*HALO)   // 14
#define HWP (HH*WW)        // 65536

__device__ __forceinline__ void gauss1d(float* g) {
    float s = 0.f;
#pragma unroll
    for (int i = 0; i < KK; ++i) {
        float d = (float)i - 3.0f;
        g[i] = __expf(-d * d / 18.0f);   // 2*sigma_g^2 = 18
        s += g[i];
    }
    float inv = 1.0f / s;
#pragma unroll
    for (int i = 0; i < KK; ++i) g[i] *= inv;
}

__global__ __launch_bounds__(256) void init_q(const float* __restrict__ unary,
                                              float* __restrict__ q) {
    int idx = blockIdx.x * 256 + threadIdx.x;
    if (idx >= BB * HWP) return;
    int b = idx >> 16;
    int pix = idx & (HWP - 1);
    const float* ub = unary + (size_t)b * CNUM * HWP + pix;
    float l[CNUM];
    float m = -1e30f;
#pragma unroll
    for (int c = 0; c < CNUM; ++c) {
        l[c] = -ub[(size_t)c * HWP];
        m = fmaxf(m, l[c]);
    }
    float s = 0.f;
#pragma unroll
    for (int c = 0; c < CNUM; ++c) {
        l[c] = __expf(l[c] - m);
        s += l[c];
    }
    float inv = 1.0f / s;
    float* qo = q + (size_t)b * CNUM * HWP + pix;
#pragma unroll
    for (int c = 0; c < CNUM; ++c) qo[(size_t)c * HWP] = l[c] * inv;
}

// Computes logits = -unary + pairwise for an 8-channel group of a 32x8 tile.
__global__ __launch_bounds__(256) void msg_kernel(const float* __restrict__ unary,
                                                  const float* __restrict__ img,
                                                  const float* __restrict__ qin,
                                                  float* __restrict__ lout) {
    __shared__ float s_img[3][LH][LW];
    __shared__ float s_q[CG][LH][LW];

    const int tid = threadIdx.x;
    const int tx = tid & (TX - 1);
    const int ty = tid >> 5;
    const int bx = blockIdx.x * TX;
    const int by = blockIdx.y * TY;
    const int b   = blockIdx.z >> 2;   // NGRP = 4
    const int grp = blockIdx.z & 3;
    const int ch0 = grp * CG;

    const float* imgb = img + (size_t)b * 3 * HWP;
    const float* qb   = qin + (size_t)b * CNUM * HWP;

    // ---- stage img (3 ch) + q (CG ch) halo tiles ----
    for (int t = tid; t < LH * LW; t += 256) {
        int r  = t / LW;
        int cc = t - r * LW;
        int gy = by + r - HALO;
        int gx = bx + cc - HALO;
        bool ok = (gy >= 0) && (gy < HH) && (gx >= 0) && (gx < WW);
        int goff = gy * WW + gx;
#pragma unroll
        for (int ch = 0; ch < 3; ++ch)
            s_img[ch][r][cc] = ok ? imgb[(size_t)ch * HWP + goff] : 0.f;
#pragma unroll
        for (int c = 0; c < CG; ++c) {
            int cg = ch0 + c;
            s_q[c][r][cc] = (ok && cg < CNUM) ? qb[(size_t)cg * HWP + goff] : 0.f;
        }
    }
    __syncthreads();

    float g[KK];
    gauss1d(g);

    const float c0 = s_img[0][ty + HALO][tx + HALO];
    const float c1 = s_img[1][ty + HALO][tx + HALO];
    const float c2 = s_img[2][ty + HALO][tx + HALO];

    float acc[CG];
#pragma unroll
    for (int c = 0; c < CG; ++c) acc[c] = 0.f;

#pragma unroll
    for (int i = 0; i < KK; ++i) {
#pragma unroll
        for (int j = 0; j < KK; ++j) {
            float d0 = s_img[0][ty + i][tx + j] - c0;
            float d1 = s_img[1][ty + i][tx + j] - c1;
            float d2 = s_img[2][ty + i][tx + j] - c2;
            float ds = d0 * d0 + d1 * d1 + d2 * d2;
            // w = gauss(i,j) * (COMPAT_G + COMPAT_B * exp(-ds / (2*SRGB^2)))
            float w = g[i] * g[j] * (3.0f + 10.0f * __expf(-ds * 0.005f));
#pragma unroll
            for (int c = 0; c < CG; ++c)
                acc[c] += w * s_q[c][ty + i][tx + j];
        }
    }

    const int pix = (by + ty) * WW + bx + tx;
    const float* ub = unary + (size_t)b * CNUM * HWP;
    float* lb = lout + (size_t)b * CNUM * HWP;
#pragma unroll
    for (int c = 0; c < CG; ++c) {
        int cg = ch0 + c;
        if (cg < CNUM)
            lb[(size_t)cg * HWP + pix] = acc[c] - ub[(size_t)cg * HWP + pix];
    }
}

// In-place channel softmax: each thread owns its pixel's 29 values.
__global__ __launch_bounds__(256) void softmax_inplace(float* __restrict__ q) {
    int idx = blockIdx.x * 256 + threadIdx.x;
    if (idx >= BB * HWP) return;
    int b = idx >> 16;
    int pix = idx & (HWP - 1);
    float* p = q + (size_t)b * CNUM * HWP + pix;
    float l[CNUM];
    float m = -1e30f;
#pragma unroll
    for (int c = 0; c < CNUM; ++c) {
        l[c] = p[(size_t)c * HWP];
        m = fmaxf(m, l[c]);
    }
    float s = 0.f;
#pragma unroll
    for (int c = 0; c < CNUM; ++c) {
        l[c] = __expf(l[c] - m);
        s += l[c];
    }
    float inv = 1.0f / s;
#pragma unroll
    for (int c = 0; c < CNUM; ++c) p[(size_t)c * HWP] = l[c] * inv;
}

extern "C" void kernel_launch(void* const* d_in, const int* in_sizes, int n_in,
                              void* d_out, int out_size, void* d_ws, size_t ws_size,
                              hipStream_t stream) {
    const float* unary = (const float*)d_in[0];
    const float* img   = (const float*)d_in[1];
    float* qA = (float*)d_ws;    // BB*CNUM*HWP*4 = 15,204,352 bytes
    float* qB = (float*)d_out;

    dim3 pgrid((BB * HWP + 255) / 256);
    init_q<<<pgrid, 256, 0, stream>>>(unary, qA);

    dim3 grid(WW / TX, HH / TY, BB * NGRP);
    // iter 1: qA -> qB
    msg_kernel<<<grid, 256, 0, stream>>>(unary, img, qA, qB);
    softmax_inplace<<<pgrid, 256, 0, stream>>>(qB);
    // iter 2: qB -> qA
    msg_kernel<<<grid, 256, 0, stream>>>(unary, img, qB, qA);
    softmax_inplace<<<pgrid, 256, 0, stream>>>(qA);
    // iter 3: qA -> qB
    msg_kernel<<<grid, 256, 0, stream>>>(unary, img, qA, qB);
    softmax_inplace<<<pgrid, 256, 0, stream>>>(qB);
    // iter 4: qB -> qA
    msg_kernel<<<grid, 256, 0, stream>>>(unary, img, qB, qA);
    softmax_inplace<<<pgrid, 256, 0, stream>>>(qA);
    // iter 5: qA -> qB = d_out
    msg_kernel<<<grid, 256, 0, stream>>>(unary, img, qA, qB);
    softmax_inplace<<<pgrid, 256, 0, stream>>>(qB);
}

// Round 3
// 140.325 us; speedup vs baseline: 19.5372x; 1.9799x over previous
//
#include <hip/hip_runtime.h>

#define CNUM 29
#define HH 256
#define WW 256
#define BB 2
#define KK 7
#define HALO 3
#define TX 32
#define TY 8
#define LW (TX + 2*HALO)   // 38
#define LH (TY + 2*HALO)   // 14
#define NPIX (LH*LW)       // 532
#define HWP (HH*WW)        // 65536

// 1-D normalized Gaussian, sigma=3.0, K=7 (precomputed: exp(-d^2/18)/sum)
__device__ __constant__ const float GW[KK] = {
    0.106287146f, 0.140321912f, 0.165770643f, 0.175240699f,
    0.165770643f, 0.140321912f, 0.106287146f};

__global__ __launch_bounds__(256) void init_q(const float* __restrict__ unary,
                                              float* __restrict__ q) {
    int idx = blockIdx.x * 256 + threadIdx.x;
    if (idx >= BB * HWP) return;
    int b = idx >> 16;
    int pix = idx & (HWP - 1);
    const float* ub = unary + (size_t)b * CNUM * HWP + pix;
    float l[CNUM];
    float m = -1e30f;
#pragma unroll
    for (int c = 0; c < CNUM; ++c) {
        l[c] = -ub[(size_t)c * HWP];
        m = fmaxf(m, l[c]);
    }
    float s = 0.f;
#pragma unroll
    for (int c = 0; c < CNUM; ++c) {
        l[c] = __expf(l[c] - m);
        s += l[c];
    }
    float inv = 1.0f / s;
    float* qo = q + (size_t)b * CNUM * HWP + pix;
#pragma unroll
    for (int c = 0; c < CNUM; ++c) qo[(size_t)c * HWP] = l[c] * inv;
}

// One full CRF iteration: message passing (49-tap bilateral+gaussian over 29 ch)
// + channel softmax, fused. q is planar [b][c][h][w] in global; LDS tile is
// channel-last [pixel][32ch] with 16B-chunk XOR swizzle for conflict-free b128.
__global__ __launch_bounds__(256, 2) void crf_iter(const float* __restrict__ unary,
                                                   const float* __restrict__ img,
                                                   const float* __restrict__ qin,
                                                   float* __restrict__ qout) {
    __shared__ float4 s_q4[NPIX * 8];   // 68,096 B
    __shared__ float s_img[3][NPIX];    //  6,384 B

    const int tid = threadIdx.x;
    const int tx = tid & (TX - 1);
    const int ty = tid >> 5;
    const int bx = blockIdx.x * TX;
    const int by = blockIdx.y * TY;
    const int b  = blockIdx.z;

    const float* qb   = qin + (size_t)b * CNUM * HWP;
    const float* imgb = img + (size_t)b * 3 * HWP;

    // ---- stage: planar global -> channel-last swizzled LDS ----
    for (int t = tid; t < NPIX; t += 256) {
        int r  = t / LW;
        int cc = t - r * LW;
        int gy = by + r - HALO;
        int gx = bx + cc - HALO;
        bool ok = (gy >= 0) & (gy < HH) & (gx >= 0) & (gx < WW);
        int goff = ok ? (gy * WW + gx) : 0;   // clamp: always-valid address
        float okf = ok ? 1.f : 0.f;
        int t8 = t * 8;
        int sw = t & 7;
#pragma unroll
        for (int ch = 0; ch < 3; ++ch)
            s_img[ch][t] = okf * imgb[(size_t)ch * HWP + goff];
#pragma unroll
        for (int g = 0; g < 8; ++g) {
            float4 v;
            v.x = (4 * g + 0 < CNUM) ? okf * qb[(size_t)(4 * g + 0) * HWP + goff] : 0.f;
            v.y = (4 * g + 1 < CNUM) ? okf * qb[(size_t)(4 * g + 1) * HWP + goff] : 0.f;
            v.z = (4 * g + 2 < CNUM) ? okf * qb[(size_t)(4 * g + 2) * HWP + goff] : 0.f;
            v.w = (4 * g + 3 < CNUM) ? okf * qb[(size_t)(4 * g + 3) * HWP + goff] : 0.f;
            s_q4[t8 + (sw ^ g)] = v;
        }
    }
    __syncthreads();

    // ---- 49-tap message passing, all 29 channels per thread ----
    const int tc = (ty + HALO) * LW + (tx + HALO);
    const float c0 = s_img[0][tc];
    const float c1 = s_img[1][tc];
    const float c2 = s_img[2][tc];

    float acc[CNUM];
#pragma unroll
    for (int c = 0; c < CNUM; ++c) acc[c] = 0.f;

#pragma unroll
    for (int i = 0; i < KK; ++i) {
#pragma unroll
        for (int j = 0; j < KK; ++j) {
            const int t = (ty + i) * LW + (tx + j);
            float d0 = s_img[0][t] - c0;
            float d1 = s_img[1][t] - c1;
            float d2 = s_img[2][t] - c2;
            float dsq = d0 * d0 + d1 * d1 + d2 * d2;
            // w = gauss * (COMPAT_G + COMPAT_B * exp(-dsq / (2*SRGB^2)))
            float w = (GW[i] * GW[j]) * (3.0f + 10.0f * __expf(dsq * -0.005f));
            const int t8 = t * 8;
            const int sw = t & 7;
#pragma unroll
            for (int g = 0; g < 8; ++g) {
                float4 qv = s_q4[t8 + (sw ^ g)];
                if (4 * g + 0 < CNUM) acc[4 * g + 0] += w * qv.x;
                if (4 * g + 1 < CNUM) acc[4 * g + 1] += w * qv.y;
                if (4 * g + 2 < CNUM) acc[4 * g + 2] += w * qv.z;
                if (4 * g + 3 < CNUM) acc[4 * g + 3] += w * qv.w;
            }
        }
    }

    // ---- fused channel softmax + planar store ----
    const int pix = (by + ty) * WW + (bx + tx);
    const float* ub = unary + (size_t)b * CNUM * HWP + pix;
    float m = -1e30f;
#pragma unroll
    for (int c = 0; c < CNUM; ++c) {
        acc[c] -= ub[(size_t)c * HWP];
        m = fmaxf(m, acc[c]);
    }
    float ssum = 0.f;
#pragma unroll
    for (int c = 0; c < CNUM; ++c) {
        acc[c] = __expf(acc[c] - m);
        ssum += acc[c];
    }
    float inv = 1.0f / ssum;
    float* qo = qout + (size_t)b * CNUM * HWP + pix;
#pragma unroll
    for (int c = 0; c < CNUM; ++c) qo[(size_t)c * HWP] = acc[c] * inv;
}

extern "C" void kernel_launch(void* const* d_in, const int* in_sizes, int n_in,
                              void* d_out, int out_size, void* d_ws, size_t ws_size,
                              hipStream_t stream) {
    const float* unary = (const float*)d_in[0];
    const float* img   = (const float*)d_in[1];
    float* qA = (float*)d_ws;    // BB*CNUM*HWP*4 = 15,204,352 bytes (proven fits)
    float* qB = (float*)d_out;   // d_out doubles as ping-pong scratch

    dim3 pgrid((BB * HWP + 255) / 256);
    init_q<<<pgrid, 256, 0, stream>>>(unary, qA);

    dim3 grid(WW / TX, HH / TY, BB);
    crf_iter<<<grid, 256, 0, stream>>>(unary, img, qA, qB);  // iter 1
    crf_iter<<<grid, 256, 0, stream>>>(unary, img, qB, qA);  // iter 2
    crf_iter<<<grid, 256, 0, stream>>>(unary, img, qA, qB);  // iter 3
    crf_iter<<<grid, 256, 0, stream>>>(unary, img, qB, qA);  // iter 4
    crf_iter<<<grid, 256, 0, stream>>>(unary, img, qA, qB);  // iter 5 -> d_out
}

// Round 4
// 132.967 us; speedup vs baseline: 20.6183x; 1.0553x over previous
//
#include <hip/hip_runtime.h>

#define CNUM 29
#define HH 256
#define WW 256
#define BB 2
#define KK 7
#define HALO 3
#define TX 32
#define TY 8
#define LW (TX + 2*HALO)   // 38
#define LH (TY + 2*HALO)   // 14
#define NPIX (LH*LW)       // 532
#define HWP (HH*WW)        // 65536

// 1-D normalized Gaussian, sigma=3.0, K=7 (exp(-d^2/18)/sum)
__device__ __constant__ const float GW[KK] = {
    0.106287146f, 0.140321912f, 0.165770643f, 0.175240699f,
    0.165770643f, 0.140321912f, 0.106287146f};

// round-to-nearest-even f32 -> bf16 pair packed as u32 (a=low/even ch, b=high/odd ch)
__device__ __forceinline__ unsigned pack_bf16(float a, float b) {
    unsigned ua = __float_as_uint(a);
    unsigned ub = __float_as_uint(b);
    ua = ua + 0x7fffu + ((ua >> 16) & 1u);
    ub = ub + 0x7fffu + ((ub >> 16) & 1u);
    return (ua >> 16) | (ub & 0xffff0000u);
}

// One full CRF iteration: 49-tap bilateral+gaussian message passing over 29 ch
// + unary + channel softmax, fused. q planar f32 in global; LDS q tile is
// channel-last packed bf16 [pixel][32ch] = 4x16B chunks, chunk-XOR-swizzled.
// FIRST=true: qin is ignored; staging computes q0 = softmax(-unary) on the fly.
template <bool FIRST>
__global__ __launch_bounds__(256) void crf_iter(const float* __restrict__ unary,
                                                const float* __restrict__ img,
                                                const float* __restrict__ qin,
                                                float* __restrict__ qout) {
    __shared__ uint4 s_q4[NPIX * 4];    // 34,048 B (32 bf16 ch/pixel)
    __shared__ float s_img[3][NPIX];    //  6,384 B

    const int tid = threadIdx.x;
    const int tx = tid & (TX - 1);
    const int ty = tid >> 5;
    const int bx = blockIdx.x * TX;
    const int by = blockIdx.y * TY;
    const int b  = blockIdx.z;

    const float* qb   = qin + (size_t)b * CNUM * HWP;
    const float* ubase = unary + (size_t)b * CNUM * HWP;
    const float* imgb = img + (size_t)b * 3 * HWP;

    // ---- stage: planar global -> channel-last bf16 swizzled LDS ----
    for (int t = tid; t < NPIX; t += 256) {
        int r  = t / LW;
        int cc = t - r * LW;
        int gy = by + r - HALO;
        int gx = bx + cc - HALO;
        bool ok = (gy >= 0) & (gy < HH) & (gx >= 0) & (gx < WW);
        int goff = ok ? (gy * WW + gx) : 0;
        float okf = ok ? 1.f : 0.f;
#pragma unroll
        for (int ch = 0; ch < 3; ++ch)
            s_img[ch][t] = okf * imgb[(size_t)ch * HWP + goff];

        float v[CNUM];
        if (FIRST) {
            float m = -1e30f;
#pragma unroll
            for (int c = 0; c < CNUM; ++c) {
                v[c] = -ubase[(size_t)c * HWP + goff];
                m = fmaxf(m, v[c]);
            }
            float s = 0.f;
#pragma unroll
            for (int c = 0; c < CNUM; ++c) {
                v[c] = __expf(v[c] - m);
                s += v[c];
            }
            float inv = okf / s;
#pragma unroll
            for (int c = 0; c < CNUM; ++c) v[c] *= inv;
        } else {
#pragma unroll
            for (int c = 0; c < CNUM; ++c)
                v[c] = okf * qb[(size_t)c * HWP + goff];
        }

        const int swz = (t >> 1) & 3;
#pragma unroll
        for (int g = 0; g < 4; ++g) {
            uint4 pk;
            pk.x = pack_bf16(8*g+0 < CNUM ? v[8*g+0] : 0.f, 8*g+1 < CNUM ? v[8*g+1] : 0.f);
            pk.y = pack_bf16(8*g+2 < CNUM ? v[8*g+2] : 0.f, 8*g+3 < CNUM ? v[8*g+3] : 0.f);
            pk.z = pack_bf16(8*g+4 < CNUM ? v[8*g+4] : 0.f, 8*g+5 < CNUM ? v[8*g+5] : 0.f);
            pk.w = pack_bf16(8*g+6 < CNUM ? v[8*g+6] : 0.f, 8*g+7 < CNUM ? v[8*g+7] : 0.f);
            s_q4[t * 4 + (g ^ swz)] = pk;
        }
    }
    __syncthreads();

    // ---- 49-tap message passing, all 29 channels per thread ----
    const int tc = (ty + HALO) * LW + (tx + HALO);
    const float c0 = s_img[0][tc];
    const float c1 = s_img[1][tc];
    const float c2 = s_img[2][tc];

    float acc[CNUM];
#pragma unroll
    for (int c = 0; c < CNUM; ++c) acc[c] = 0.f;

#pragma unroll
    for (int i = 0; i < KK; ++i) {
#pragma unroll
        for (int j = 0; j < KK; ++j) {
            const int t = (ty + i) * LW + (tx + j);
            float d0 = s_img[0][t] - c0;
            float d1 = s_img[1][t] - c1;
            float d2 = s_img[2][t] - c2;
            float dsq = d0 * d0 + d1 * d1 + d2 * d2;
            // w = gauss * (COMPAT_G + COMPAT_B * exp(-dsq / (2*SRGB^2)))
            float w = (GW[i] * GW[j]) * (3.0f + 10.0f * __expf(dsq * -0.005f));
            const int t4 = t * 4;
            const int swz = (t >> 1) & 3;
#pragma unroll
            for (int g = 0; g < 4; ++g) {
                uint4 qc = s_q4[t4 + (g ^ swz)];
#pragma unroll
                for (int k = 0; k < 4; ++k) {
                    unsigned u = (&qc.x)[k];
                    int ce = 8 * g + 2 * k;
                    if (ce < CNUM)
                        acc[ce] += w * __uint_as_float(u << 16);
                    if (ce + 1 < CNUM)
                        acc[ce + 1] += w * __uint_as_float(u & 0xffff0000u);
                }
            }
        }
    }

    // ---- fused unary + channel softmax + planar store ----
    const int pix = (by + ty) * WW + (bx + tx);
    const float* ub = ubase + pix;
    float m = -1e30f;
#pragma unroll
    for (int c = 0; c < CNUM; ++c) {
        acc[c] -= ub[(size_t)c * HWP];
        m = fmaxf(m, acc[c]);
    }
    float ssum = 0.f;
#pragma unroll
    for (int c = 0; c < CNUM; ++c) {
        acc[c] = __expf(acc[c] - m);
        ssum += acc[c];
    }
    float inv = 1.0f / ssum;
    float* qo = qout + (size_t)b * CNUM * HWP + pix;
#pragma unroll
    for (int c = 0; c < CNUM; ++c) qo[(size_t)c * HWP] = acc[c] * inv;
}

extern "C" void kernel_launch(void* const* d_in, const int* in_sizes, int n_in,
                              void* d_out, int out_size, void* d_ws, size_t ws_size,
                              hipStream_t stream) {
    const float* unary = (const float*)d_in[0];
    const float* img   = (const float*)d_in[1];
    float* qA = (float*)d_ws;    // BB*CNUM*HWP*4 = 15,204,352 bytes
    float* qB = (float*)d_out;   // d_out doubles as ping-pong scratch

    dim3 grid(WW / TX, HH / TY, BB);
    crf_iter<true ><<<grid, 256, 0, stream>>>(unary, img, qB /*unused*/, qB); // iter 1
    crf_iter<false><<<grid, 256, 0, stream>>>(unary, img, qB, qA);            // iter 2
    crf_iter<false><<<grid, 256, 0, stream>>>(unary, img, qA, qB);            // iter 3
    crf_iter<false><<<grid, 256, 0, stream>>>(unary, img, qB, qA);            // iter 4
    crf_iter<false><<<grid, 256, 0, stream>>>(unary, img, qA, qB);            // iter 5 -> d_out
}